// Round 19
// baseline (188.315 us; speedup 1.0000x reference)
//
#include <hip/hip_runtime.h>

// Fused transformer block in bf16 MFMA (gfx950 16x16x32), fp32 residuals.
// One wave processes M-tiles of 16 seq-rows (2 seqs) end-to-end; THREE tiles
// (A/B/C) interleaved per iteration for ILP. Wave-private LDS contexts
// (in-order LDS pipe per wave) -> NO barriers.
//
// Round-19 = round-14/18 champion (181us, verified PASS x2) + ONE delta:
//  - s_setprio(1)/(0) around the MFMA-dense clusters (qkv, ff1+ff2).
//    T5 mechanism: pays when resident waves are at DIFFERENT phases (attn
//    +4-7%, m191); our barrier-free 2-waves/SIMD kernel is that regime.
//    Pure scheduler hint -> zero correctness risk.
// Session ledger (unchanged):
//  - launch_bounds(.,>=2): 3-for-3 NaN -> permanently off the table.
//  - may_alias on all LDS accesses required; strides must stay 16B-multiples.
//  - occupancy register-pinned at 2 waves/SIMD; streaming/split/stride-fix
//    all measured regressions.

typedef __attribute__((ext_vector_type(8))) short        bf16x8;
typedef __attribute__((ext_vector_type(4))) float        f32x4;
typedef __attribute__((ext_vector_type(4))) int          i32x4;
typedef __attribute__((ext_vector_type(2))) unsigned int u32x2;

// may_alias views for LDS (and any punned) memory access
typedef i32x4 __attribute__((may_alias)) i32x4_a;
typedef u32x2 __attribute__((may_alias)) u32x2_a;
typedef f32x4 __attribute__((may_alias)) f32x4_a;

#define THREADS 256
#define TPB 48   // tiles per block (4 waves x 12)
#define TPW 12   // tiles per wave (4 iterations x 3 contexts)

// per-context LDS offsets (bytes), interval-colored (round-9/10 verified):
#define LDS_P2    0      // 2x[16] stride 80 (2560B) scores -> pv
#define LDS_QK    2560   // [16] stride 144 (2304B)  qkv -> scores
#define LDS_ATTN  2560   // [16] stride 80  (1280B)  pv -> proj   (over QK)
#define LDS_VT    4864   // [32] stride 48  (1536B)  qkv -> pv
#define LDS_X2    4864   // [16] stride 80  (1280B)  proj -> ff1  (over VT)
#define LDS_HID   0      // [16] stride 272 (4352B)  ff1 -> ff2   (over P2/QK/ATTN)
#define LDS_CTX   6656

__device__ __forceinline__ unsigned pk_bf16(float a, float b) {
    unsigned r;
    asm("v_cvt_pk_bf16_f32 %0, %1, %2" : "=v"(r) : "v"(a), "v"(b));
    return r;
}

union frag_u { i32x4 i; bf16x8 b; };

// A/B-frag gather of a weight matrix column: elem j = p[(8g+j)*ldk] * s
__device__ __forceinline__ bf16x8 gather_w(const float* p, int ldk, int g, float s) {
    frag_u r;
    #pragma unroll
    for (int jj = 0; jj < 4; ++jj) {
        float a = p[(8 * g + 2 * jj) * ldk] * s;
        float b = p[(8 * g + 2 * jj + 1) * ldk] * s;
        r.i[jj] = (int)pk_bf16(a, b);
    }
    return r.b;
}

// ---------------- phase helpers (round-14 verified bodies, may_alias LDS) ---

__device__ __forceinline__ void ph_qkv(char* Wc, int c, int g,
                                       const bf16x8 (&wqk)[4], const bf16x8 (&wv)[2],
                                       const bf16x8& xf) {
    const f32x4 z4 = {0.f, 0.f, 0.f, 0.f};
    #pragma unroll
    for (int n = 0; n < 4; ++n) {
        f32x4 qc = __builtin_amdgcn_mfma_f32_16x16x32_bf16(wqk[n], xf, z4, 0, 0, 0);
        u32x2 w64 = { pk_bf16(qc[0], qc[1]), pk_bf16(qc[2], qc[3]) };
        *(u32x2_a*)(void*)(Wc + LDS_QK + c * 144 + (16 * n + 4 * g) * 2) = w64;
    }
    #pragma unroll
    for (int n = 0; n < 2; ++n) {
        f32x4 vc = __builtin_amdgcn_mfma_f32_16x16x32_bf16(xf, wv[n], z4, 0, 0, 0);
        u32x2 w64 = { pk_bf16(vc[0], vc[1]), pk_bf16(vc[2], vc[3]) };
        *(u32x2_a*)(void*)(Wc + LDS_VT + (16 * n + c) * 48 + 8 * g) = w64;
    }
}

__device__ __forceinline__ void ph_scores(char* Wc, int c, int g,
                                          const f32x4& mf, const i32x4& mQK) {
    const f32x4 z4 = {0.f, 0.f, 0.f, 0.f};
    #pragma unroll
    for (int h = 0; h < 4; ++h) {
        frag_u kf, qf;
        kf.i = *(const i32x4_a*)(const void*)(Wc + LDS_QK + c * 144 + 32 * h);
        qf.i = *(const i32x4_a*)(const void*)(Wc + LDS_QK + c * 144 + 32 * h + 16);
        kf.i &= mQK; qf.i &= mQK;
        f32x4 sT = __builtin_amdgcn_mfma_f32_16x16x32_bf16(kf.b, qf.b, z4, 0, 0, 0);
        float e0 = __builtin_amdgcn_exp2f(sT[0]) * mf[0];
        float e1 = __builtin_amdgcn_exp2f(sT[1]) * mf[1];
        float e2 = __builtin_amdgcn_exp2f(sT[2]) * mf[2];
        float e3 = __builtin_amdgcn_exp2f(sT[3]) * mf[3];
        float s = (e0 + e1) + (e2 + e3);
        s += __shfl_xor(s, 16);
        s += __shfl_xor(s, 32);
        float rs = __builtin_amdgcn_rcpf(s);
        u32x2 w64 = { pk_bf16(e0 * rs, e1 * rs), pk_bf16(e2 * rs, e3 * rs) };
        *(u32x2_a*)(void*)(Wc + LDS_P2 + (h >> 1) * 1280 + c * 80 + ((h & 1) * 16 + 4 * g) * 2) = w64;
    }
}

__device__ __forceinline__ void ph_pv(char* Wc, int c, int g, const i32x4& mPV) {
    const f32x4 z4 = {0.f, 0.f, 0.f, 0.f};
    #pragma unroll
    for (int p = 0; p < 2; ++p) {
        frag_u va, pb;
        va.i = *(const i32x4_a*)(const void*)(Wc + LDS_VT + (16 * p + c) * 48 + (g & 1) * 16);
        va.i &= mPV;
        pb.i = *(const i32x4_a*)(const void*)(Wc + LDS_P2 + p * 1280 + c * 80 + g * 16);
        f32x4 pv = __builtin_amdgcn_mfma_f32_16x16x32_bf16(va.b, pb.b, z4, 0, 0, 0);
        u32x2 w64 = { pk_bf16(pv[0], pv[1]), pk_bf16(pv[2], pv[3]) };
        *(u32x2_a*)(void*)(Wc + LDS_ATTN + c * 80 + (16 * p + 4 * g) * 2) = w64;
    }
}

__device__ __forceinline__ void ph_proj(char* Wc, int c, int g, const bf16x8 (&wp)[2],
                                        const f32x4& rx0, const f32x4& rx1, f32x4 (&x2c)[2]) {
    frag_u af; af.i = *(const i32x4_a*)(const void*)(Wc + LDS_ATTN + c * 80 + g * 16);
    #pragma unroll
    for (int n = 0; n < 2; ++n) {
        const f32x4 z4 = {0.f, 0.f, 0.f, 0.f};
        f32x4 pc = __builtin_amdgcn_mfma_f32_16x16x32_bf16(wp[n], af.b, z4, 0, 0, 0);
        f32x4 rx = (n == 0) ? rx0 : rx1;
        #pragma unroll
        for (int r = 0; r < 4; ++r) x2c[n][r] = pc[r] + rx[r];
        u32x2 w64 = { pk_bf16(x2c[n][0], x2c[n][1]), pk_bf16(x2c[n][2], x2c[n][3]) };
        *(u32x2_a*)(void*)(Wc + LDS_X2 + c * 80 + (16 * n + 4 * g) * 2) = w64;
    }
}

__device__ __forceinline__ void ph_ff1h(char* Wc, int c, int g,
                                        const bf16x8 (&w1h)[4], int n0,
                                        const bf16x8& bfX) {
    #pragma unroll
    for (int k = 0; k < 4; ++k) {
        const int n = n0 + k;
        const f32x4 z4 = {0.f, 0.f, 0.f, 0.f};
        f32x4 hc = __builtin_amdgcn_mfma_f32_16x16x32_bf16(w1h[k], bfX, z4, 0, 0, 0);
        #pragma unroll
        for (int r = 0; r < 4; ++r) hc[r] = fmaxf(hc[r], 0.f);
        u32x2 w64 = { pk_bf16(hc[0], hc[1]), pk_bf16(hc[2], hc[3]) };
        *(u32x2_a*)(void*)(Wc + LDS_HID + c * 272 + (16 * n + 4 * g) * 2) = w64;
    }
}

// FF2 with DIRECT C^T store: lane (g,c) stores ch {4g..} and {16+4g..} of row c
__device__ __forceinline__ void ph_ff2_store(char* Wc, int c, int g,
                                             const bf16x8 (&w2a)[4], const bf16x8 (&w2b)[4],
                                             const f32x4 (&x2c)[2], float* outg, bool ok) {
    frag_u hf0, hf1, hf2, hf3;
    hf0.i = *(const i32x4_a*)(const void*)(Wc + LDS_HID + c * 272 + 0 * 64 + g * 16);
    hf1.i = *(const i32x4_a*)(const void*)(Wc + LDS_HID + c * 272 + 1 * 64 + g * 16);
    hf2.i = *(const i32x4_a*)(const void*)(Wc + LDS_HID + c * 272 + 2 * 64 + g * 16);
    hf3.i = *(const i32x4_a*)(const void*)(Wc + LDS_HID + c * 272 + 3 * 64 + g * 16);
    {
        f32x4 oc = x2c[0];
        oc = __builtin_amdgcn_mfma_f32_16x16x32_bf16(w2a[0], hf0.b, oc, 0, 0, 0);
        oc = __builtin_amdgcn_mfma_f32_16x16x32_bf16(w2a[1], hf1.b, oc, 0, 0, 0);
        oc = __builtin_amdgcn_mfma_f32_16x16x32_bf16(w2a[2], hf2.b, oc, 0, 0, 0);
        oc = __builtin_amdgcn_mfma_f32_16x16x32_bf16(w2a[3], hf3.b, oc, 0, 0, 0);
        if (ok) *(f32x4_a*)(outg + c * 32 + 4 * g) = oc;
    }
    {
        f32x4 oc = x2c[1];
        oc = __builtin_amdgcn_mfma_f32_16x16x32_bf16(w2b[0], hf0.b, oc, 0, 0, 0);
        oc = __builtin_amdgcn_mfma_f32_16x16x32_bf16(w2b[1], hf1.b, oc, 0, 0, 0);
        oc = __builtin_amdgcn_mfma_f32_16x16x32_bf16(w2b[2], hf2.b, oc, 0, 0, 0);
        oc = __builtin_amdgcn_mfma_f32_16x16x32_bf16(w2b[3], hf3.b, oc, 0, 0, 0);
        if (ok) *(f32x4_a*)(outg + c * 32 + 16 + 4 * g) = oc;
    }
}

// ---------------------------------------------------------------------------

__global__ __launch_bounds__(THREADS)
void block_mfma3(const float* __restrict__ X,
                 const float* __restrict__ Wattn,   // (4,32,24) d: k0..7 q8..15 v16..23
                 const float* __restrict__ Wproj,   // (32,32) [in][out]
                 const float* __restrict__ Wff1,    // (32,128)
                 const float* __restrict__ Wff2,    // (128,32)
                 float* __restrict__ Out,
                 int ntiles)
{
    __shared__ __align__(16) char smem[4 * 3 * LDS_CTX];   // 79,872 B -> 2 blocks/CU

    const int lane = threadIdx.x & 63;
    const int wid  = threadIdx.x >> 6;
    const int g    = lane >> 4;
    const int c    = lane & 15;
    char* WA = smem + wid * (3 * LDS_CTX);
    char* WB = WA + LDS_CTX;
    char* WC = WB + LDS_CTX;

    const float wscale = 0.5050098f;   // sqrt(32^-0.5 * log2(e))

    // ---- resident weight fragments (26 x bf16x8 = 104 regs) ----
    bf16x8 wqk[4], wv[2], wp[2], w1lo[4], w1hi[4], w2lo[4], w2hi[4];
    #pragma unroll
    for (int n = 0; n < 4; ++n)
        wqk[n] = gather_w(Wattn + n * 768 + c, 24, g, wscale);
    #pragma unroll
    for (int n = 0; n < 2; ++n) {
        int vch = 16 * n + c;
        wv[n] = gather_w(Wattn + (vch >> 3) * 768 + 16 + (vch & 7), 24, g, 1.f);
    }
    #pragma unroll
    for (int n = 0; n < 2; ++n)
        wp[n] = gather_w(Wproj + 16 * n + c, 32, g, 1.f);
    #pragma unroll
    for (int k = 0; k < 4; ++k) {
        w1lo[k] = gather_w(Wff1 + 16 * k + c, 128, g, 1.f);
        w1hi[k] = gather_w(Wff1 + 16 * (4 + k) + c, 128, g, 1.f);
        w2lo[k] = gather_w(Wff2 + k * 1024 + c, 32, g, 1.f);
        w2hi[k] = gather_w(Wff2 + k * 1024 + 16 + c, 32, g, 1.f);
    }

    // ---- per-lane constant masks ----
    f32x4 mf;
    #pragma unroll
    for (int r = 0; r < 4; ++r) {
        int key = 4 * g + r;
        mf[r] = ((key >> 3) == (c >> 3) && (key & 7) <= (c & 7)) ? 1.f : 0.f;
    }
    const int b0 = (lane < 16) ? -1 : 0;
    const int b1 = (((lane >> 3) & 1) == ((lane >> 5) & 1)) ? -1 : 0;
    const i32x4 mQK = {b0, b0, b0, b0};
    const i32x4 mPV = {b1, b1, b1, b1};

    const int tile0 = blockIdx.x * TPB + wid * TPW;
    if (tile0 >= ntiles) return;

    // prefetch triple 0's X B-frag sources: lane (g,c) needs X[c][8g..8g+7]
    int pA = tile0;
    int pB = (tile0 + 1 < ntiles) ? tile0 + 1 : ntiles - 1;
    int pC = (tile0 + 2 < ntiles) ? tile0 + 2 : ntiles - 1;
    f32x4 xrA0 = *(const f32x4*)(X + (size_t)pA * 512 + c * 32 + 8 * g);
    f32x4 xrA1 = *(const f32x4*)(X + (size_t)pA * 512 + c * 32 + 8 * g + 4);
    f32x4 xrB0 = *(const f32x4*)(X + (size_t)pB * 512 + c * 32 + 8 * g);
    f32x4 xrB1 = *(const f32x4*)(X + (size_t)pB * 512 + c * 32 + 8 * g + 4);
    f32x4 xrC0 = *(const f32x4*)(X + (size_t)pC * 512 + c * 32 + 8 * g);
    f32x4 xrC1 = *(const f32x4*)(X + (size_t)pC * 512 + c * 32 + 8 * g + 4);

    #pragma unroll 1
    for (int it = 0; it < TPW; it += 3) {
        const int iA = tile0 + it;
        const int iB = tile0 + it + 1;
        const int iC = tile0 + it + 2;
        const int ttA = (iA < ntiles) ? iA : ntiles - 1;
        const int ttB = (iB < ntiles) ? iB : ntiles - 1;
        const int ttC = (iC < ntiles) ? iC : ntiles - 1;
        const float* xgA = X + (size_t)ttA * 512;
        const float* xgB = X + (size_t)ttB * 512;
        const float* xgC = X + (size_t)ttC * 512;

        // residuals at C^T points (consumed in proj; latency covered by qkv+scores)
        f32x4 rxA0 = *(const f32x4*)(xgA + c * 32 + 4 * g);
        f32x4 rxA1 = *(const f32x4*)(xgA + c * 32 + 16 + 4 * g);
        f32x4 rxB0 = *(const f32x4*)(xgB + c * 32 + 4 * g);
        f32x4 rxB1 = *(const f32x4*)(xgB + c * 32 + 16 + 4 * g);
        f32x4 rxC0 = *(const f32x4*)(xgC + c * 32 + 4 * g);
        f32x4 rxC1 = *(const f32x4*)(xgC + c * 32 + 16 + 4 * g);

        // build X frags from prefetched sources (same convert path as verified)
        frag_u xfA, xfB, xfC;
        xfA.i = i32x4{ (int)pk_bf16(xrA0[0], xrA0[1]), (int)pk_bf16(xrA0[2], xrA0[3]),
                       (int)pk_bf16(xrA1[0], xrA1[1]), (int)pk_bf16(xrA1[2], xrA1[3]) };
        xfB.i = i32x4{ (int)pk_bf16(xrB0[0], xrB0[1]), (int)pk_bf16(xrB0[2], xrB0[3]),
                       (int)pk_bf16(xrB1[0], xrB1[1]), (int)pk_bf16(xrB1[2], xrB1[3]) };
        xfC.i = i32x4{ (int)pk_bf16(xrC0[0], xrC0[1]), (int)pk_bf16(xrC0[2], xrC0[3]),
                       (int)pk_bf16(xrC1[0], xrC1[1]), (int)pk_bf16(xrC1[2], xrC1[3]) };

        // prefetch next triple's X frag sources
        {
            int nA = (it + 3 < TPW && iA + 3 < ntiles) ? iA + 3 : ttA;
            int nB = (it + 4 < TPW && iB + 3 < ntiles) ? iB + 3 : ttB;
            int nC = (it + 5 < TPW && iC + 3 < ntiles) ? iC + 3 : ttC;
            xrA0 = *(const f32x4*)(X + (size_t)nA * 512 + c * 32 + 8 * g);
            xrA1 = *(const f32x4*)(X + (size_t)nA * 512 + c * 32 + 8 * g + 4);
            xrB0 = *(const f32x4*)(X + (size_t)nB * 512 + c * 32 + 8 * g);
            xrB1 = *(const f32x4*)(X + (size_t)nB * 512 + c * 32 + 8 * g + 4);
            xrC0 = *(const f32x4*)(X + (size_t)nC * 512 + c * 32 + 8 * g);
            xrC1 = *(const f32x4*)(X + (size_t)nC * 512 + c * 32 + 8 * g + 4);
        }

        // ---- MFMA-dense cluster: qkv (18 MFMA) ----
        __builtin_amdgcn_s_setprio(1);
        ph_qkv(WA, c, g, wqk, wv, xfA.b);
        ph_qkv(WB, c, g, wqk, wv, xfB.b);
        ph_qkv(WC, c, g, wqk, wv, xfC.b);
        __builtin_amdgcn_s_setprio(0);

        ph_scores(WA, c, g, mf, mQK);
        ph_scores(WB, c, g, mf, mQK);
        ph_scores(WC, c, g, mf, mQK);

        ph_pv(WA, c, g, mPV);
        ph_pv(WB, c, g, mPV);
        ph_pv(WC, c, g, mPV);

        f32x4 x2A[2], x2B[2], x2C[2];
        ph_proj(WA, c, g, wp, rxA0, rxA1, x2A);
        ph_proj(WB, c, g, wp, rxB0, rxB1, x2B);
        ph_proj(WC, c, g, wp, rxC0, rxC1, x2C);

        frag_u bfA; bfA.i = *(const i32x4_a*)(const void*)(WA + LDS_X2 + c * 80 + g * 16);
        frag_u bfB; bfB.i = *(const i32x4_a*)(const void*)(WB + LDS_X2 + c * 80 + g * 16);
        frag_u bfC; bfC.i = *(const i32x4_a*)(const void*)(WC + LDS_X2 + c * 80 + g * 16);

        // ---- MFMA-dense cluster: ff1 + ff2 (48 MFMA) ----
        __builtin_amdgcn_s_setprio(1);
        ph_ff1h(WA, c, g, w1lo, 0, bfA.b);
        ph_ff1h(WB, c, g, w1lo, 0, bfB.b);
        ph_ff1h(WC, c, g, w1lo, 0, bfC.b);
        ph_ff1h(WA, c, g, w1hi, 4, bfA.b);
        ph_ff1h(WB, c, g, w1hi, 4, bfB.b);
        ph_ff1h(WC, c, g, w1hi, 4, bfC.b);

        ph_ff2_store(WA, c, g, w2lo, w2hi, x2A, Out + (size_t)ttA * 512, iA < ntiles);
        ph_ff2_store(WB, c, g, w2lo, w2hi, x2B, Out + (size_t)ttB * 512, iB < ntiles);
        ph_ff2_store(WC, c, g, w2lo, w2hi, x2C, Out + (size_t)ttC * 512, iC < ntiles);
        __builtin_amdgcn_s_setprio(0);
    }
}

extern "C" void kernel_launch(void* const* d_in, const int* in_sizes, int n_in,
                              void* d_out, int out_size, void* d_ws, size_t ws_size,
                              hipStream_t stream) {
    (void)n_in; (void)out_size; (void)d_ws; (void)ws_size;
    const float* X     = (const float*)d_in[0];
    const float* Wattn = (const float*)d_in[1];
    const float* Wproj = (const float*)d_in[2];
    const float* Wff1  = (const float*)d_in[3];
    const float* Wff2  = (const float*)d_in[4];
    float* Out = (float*)d_out;

    const int nseq   = in_sizes[0] / 256;   // (b, 8, 32)
    const int ntiles = nseq / 2;            // 16 rows per tile
    const int blocks = (ntiles + TPB - 1) / TPB;
    block_mfma3<<<dim3(blocks), dim3(THREADS), 0, stream>>>(
        X, Wattn, Wproj, Wff1, Wff2, Out, ntiles);
}

// Round 20
// 179.816 us; speedup vs baseline: 1.0473x; 1.0473x over previous
//
#include <hip/hip_runtime.h>

// Fused transformer block in bf16 MFMA (gfx950 16x16x32), fp32 residuals.
// One wave processes M-tiles of 16 seq-rows (2 seqs) end-to-end; THREE tiles
// (A/B/C) interleaved per iteration for ILP. Wave-private LDS contexts
// (in-order LDS pipe per wave) -> NO barriers.
//
// FINAL = round-14 champion (180.4us r14 / 181.1us r18, verified PASS x2).
// Complete session ledger:
//  - r19 setprio around MFMA clusters: -4% (starves the sibling wave at
//    2 waves/SIMD; m190-negative regime, not m191-positive) -> reverted.
//  - launch_bounds(.,>=2): 3-for-3 NaN (r11/r13/r17, with AND without
//    may_alias) -> forced-budget regalloc breaks the barrier-free
//    aliased-LDS design; permanently off the table.
//  - may_alias on all LDS accesses REQUIRED (r13 NaN -> r14 pass).
//  - LDS strides must stay 16B-multiples (r16: 148/276 split b128 ops, 2x
//    regression); 144/272's residual conflicts are structural.
//  - VALU trim (r15): VALUBusy 42->36 but flat -> latency-bound.
//  - occupancy register-pinned at 2 waves/SIMD (~212 unified regs incl.
//    AGPR frags); streaming FF weights unforced gets hoisted (r7/r9 slower).
//  - split kernels (r12): slower (+x2 round trip, 2nd dispatch).

typedef __attribute__((ext_vector_type(8))) short        bf16x8;
typedef __attribute__((ext_vector_type(4))) float        f32x4;
typedef __attribute__((ext_vector_type(4))) int          i32x4;
typedef __attribute__((ext_vector_type(2))) unsigned int u32x2;

// may_alias views for LDS (and any punned) memory access
typedef i32x4 __attribute__((may_alias)) i32x4_a;
typedef u32x2 __attribute__((may_alias)) u32x2_a;
typedef f32x4 __attribute__((may_alias)) f32x4_a;

#define THREADS 256
#define TPB 48   // tiles per block (4 waves x 12)
#define TPW 12   // tiles per wave (4 iterations x 3 contexts)

// per-context LDS offsets (bytes), interval-colored (round-9/10 verified):
#define LDS_P2    0      // 2x[16] stride 80 (2560B) scores -> pv
#define LDS_QK    2560   // [16] stride 144 (2304B)  qkv -> scores
#define LDS_ATTN  2560   // [16] stride 80  (1280B)  pv -> proj   (over QK)
#define LDS_VT    4864   // [32] stride 48  (1536B)  qkv -> pv
#define LDS_X2    4864   // [16] stride 80  (1280B)  proj -> ff1  (over VT)
#define LDS_HID   0      // [16] stride 272 (4352B)  ff1 -> ff2   (over P2/QK/ATTN)
#define LDS_CTX   6656

__device__ __forceinline__ unsigned pk_bf16(float a, float b) {
    unsigned r;
    asm("v_cvt_pk_bf16_f32 %0, %1, %2" : "=v"(r) : "v"(a), "v"(b));
    return r;
}

union frag_u { i32x4 i; bf16x8 b; };

// A/B-frag gather of a weight matrix column: elem j = p[(8g+j)*ldk] * s
__device__ __forceinline__ bf16x8 gather_w(const float* p, int ldk, int g, float s) {
    frag_u r;
    #pragma unroll
    for (int jj = 0; jj < 4; ++jj) {
        float a = p[(8 * g + 2 * jj) * ldk] * s;
        float b = p[(8 * g + 2 * jj + 1) * ldk] * s;
        r.i[jj] = (int)pk_bf16(a, b);
    }
    return r.b;
}

// ---------------- phase helpers (round-14 verified bodies, may_alias LDS) ---

__device__ __forceinline__ void ph_qkv(char* Wc, int c, int g,
                                       const bf16x8 (&wqk)[4], const bf16x8 (&wv)[2],
                                       const bf16x8& xf) {
    const f32x4 z4 = {0.f, 0.f, 0.f, 0.f};
    #pragma unroll
    for (int n = 0; n < 4; ++n) {
        f32x4 qc = __builtin_amdgcn_mfma_f32_16x16x32_bf16(wqk[n], xf, z4, 0, 0, 0);
        u32x2 w64 = { pk_bf16(qc[0], qc[1]), pk_bf16(qc[2], qc[3]) };
        *(u32x2_a*)(void*)(Wc + LDS_QK + c * 144 + (16 * n + 4 * g) * 2) = w64;
    }
    #pragma unroll
    for (int n = 0; n < 2; ++n) {
        f32x4 vc = __builtin_amdgcn_mfma_f32_16x16x32_bf16(xf, wv[n], z4, 0, 0, 0);
        u32x2 w64 = { pk_bf16(vc[0], vc[1]), pk_bf16(vc[2], vc[3]) };
        *(u32x2_a*)(void*)(Wc + LDS_VT + (16 * n + c) * 48 + 8 * g) = w64;
    }
}

__device__ __forceinline__ void ph_scores(char* Wc, int c, int g,
                                          const f32x4& mf, const i32x4& mQK) {
    const f32x4 z4 = {0.f, 0.f, 0.f, 0.f};
    #pragma unroll
    for (int h = 0; h < 4; ++h) {
        frag_u kf, qf;
        kf.i = *(const i32x4_a*)(const void*)(Wc + LDS_QK + c * 144 + 32 * h);
        qf.i = *(const i32x4_a*)(const void*)(Wc + LDS_QK + c * 144 + 32 * h + 16);
        kf.i &= mQK; qf.i &= mQK;
        f32x4 sT = __builtin_amdgcn_mfma_f32_16x16x32_bf16(kf.b, qf.b, z4, 0, 0, 0);
        float e0 = __builtin_amdgcn_exp2f(sT[0]) * mf[0];
        float e1 = __builtin_amdgcn_exp2f(sT[1]) * mf[1];
        float e2 = __builtin_amdgcn_exp2f(sT[2]) * mf[2];
        float e3 = __builtin_amdgcn_exp2f(sT[3]) * mf[3];
        float s = (e0 + e1) + (e2 + e3);
        s += __shfl_xor(s, 16);
        s += __shfl_xor(s, 32);
        float rs = __builtin_amdgcn_rcpf(s);
        u32x2 w64 = { pk_bf16(e0 * rs, e1 * rs), pk_bf16(e2 * rs, e3 * rs) };
        *(u32x2_a*)(void*)(Wc + LDS_P2 + (h >> 1) * 1280 + c * 80 + ((h & 1) * 16 + 4 * g) * 2) = w64;
    }
}

__device__ __forceinline__ void ph_pv(char* Wc, int c, int g, const i32x4& mPV) {
    const f32x4 z4 = {0.f, 0.f, 0.f, 0.f};
    #pragma unroll
    for (int p = 0; p < 2; ++p) {
        frag_u va, pb;
        va.i = *(const i32x4_a*)(const void*)(Wc + LDS_VT + (16 * p + c) * 48 + (g & 1) * 16);
        va.i &= mPV;
        pb.i = *(const i32x4_a*)(const void*)(Wc + LDS_P2 + p * 1280 + c * 80 + g * 16);
        f32x4 pv = __builtin_amdgcn_mfma_f32_16x16x32_bf16(va.b, pb.b, z4, 0, 0, 0);
        u32x2 w64 = { pk_bf16(pv[0], pv[1]), pk_bf16(pv[2], pv[3]) };
        *(u32x2_a*)(void*)(Wc + LDS_ATTN + c * 80 + (16 * p + 4 * g) * 2) = w64;
    }
}

__device__ __forceinline__ void ph_proj(char* Wc, int c, int g, const bf16x8 (&wp)[2],
                                        const f32x4& rx0, const f32x4& rx1, f32x4 (&x2c)[2]) {
    frag_u af; af.i = *(const i32x4_a*)(const void*)(Wc + LDS_ATTN + c * 80 + g * 16);
    #pragma unroll
    for (int n = 0; n < 2; ++n) {
        const f32x4 z4 = {0.f, 0.f, 0.f, 0.f};
        f32x4 pc = __builtin_amdgcn_mfma_f32_16x16x32_bf16(wp[n], af.b, z4, 0, 0, 0);
        f32x4 rx = (n == 0) ? rx0 : rx1;
        #pragma unroll
        for (int r = 0; r < 4; ++r) x2c[n][r] = pc[r] + rx[r];
        u32x2 w64 = { pk_bf16(x2c[n][0], x2c[n][1]), pk_bf16(x2c[n][2], x2c[n][3]) };
        *(u32x2_a*)(void*)(Wc + LDS_X2 + c * 80 + (16 * n + 4 * g) * 2) = w64;
    }
}

__device__ __forceinline__ void ph_ff1h(char* Wc, int c, int g,
                                        const bf16x8 (&w1h)[4], int n0,
                                        const bf16x8& bfX) {
    #pragma unroll
    for (int k = 0; k < 4; ++k) {
        const int n = n0 + k;
        const f32x4 z4 = {0.f, 0.f, 0.f, 0.f};
        f32x4 hc = __builtin_amdgcn_mfma_f32_16x16x32_bf16(w1h[k], bfX, z4, 0, 0, 0);
        #pragma unroll
        for (int r = 0; r < 4; ++r) hc[r] = fmaxf(hc[r], 0.f);
        u32x2 w64 = { pk_bf16(hc[0], hc[1]), pk_bf16(hc[2], hc[3]) };
        *(u32x2_a*)(void*)(Wc + LDS_HID + c * 272 + (16 * n + 4 * g) * 2) = w64;
    }
}

// FF2 with DIRECT C^T store: lane (g,c) stores ch {4g..} and {16+4g..} of row c
__device__ __forceinline__ void ph_ff2_store(char* Wc, int c, int g,
                                             const bf16x8 (&w2a)[4], const bf16x8 (&w2b)[4],
                                             const f32x4 (&x2c)[2], float* outg, bool ok) {
    frag_u hf0, hf1, hf2, hf3;
    hf0.i = *(const i32x4_a*)(const void*)(Wc + LDS_HID + c * 272 + 0 * 64 + g * 16);
    hf1.i = *(const i32x4_a*)(const void*)(Wc + LDS_HID + c * 272 + 1 * 64 + g * 16);
    hf2.i = *(const i32x4_a*)(const void*)(Wc + LDS_HID + c * 272 + 2 * 64 + g * 16);
    hf3.i = *(const i32x4_a*)(const void*)(Wc + LDS_HID + c * 272 + 3 * 64 + g * 16);
    {
        f32x4 oc = x2c[0];
        oc = __builtin_amdgcn_mfma_f32_16x16x32_bf16(w2a[0], hf0.b, oc, 0, 0, 0);
        oc = __builtin_amdgcn_mfma_f32_16x16x32_bf16(w2a[1], hf1.b, oc, 0, 0, 0);
        oc = __builtin_amdgcn_mfma_f32_16x16x32_bf16(w2a[2], hf2.b, oc, 0, 0, 0);
        oc = __builtin_amdgcn_mfma_f32_16x16x32_bf16(w2a[3], hf3.b, oc, 0, 0, 0);
        if (ok) *(f32x4_a*)(outg + c * 32 + 4 * g) = oc;
    }
    {
        f32x4 oc = x2c[1];
        oc = __builtin_amdgcn_mfma_f32_16x16x32_bf16(w2b[0], hf0.b, oc, 0, 0, 0);
        oc = __builtin_amdgcn_mfma_f32_16x16x32_bf16(w2b[1], hf1.b, oc, 0, 0, 0);
        oc = __builtin_amdgcn_mfma_f32_16x16x32_bf16(w2b[2], hf2.b, oc, 0, 0, 0);
        oc = __builtin_amdgcn_mfma_f32_16x16x32_bf16(w2b[3], hf3.b, oc, 0, 0, 0);
        if (ok) *(f32x4_a*)(outg + c * 32 + 16 + 4 * g) = oc;
    }
}

// ---------------------------------------------------------------------------

__global__ __launch_bounds__(THREADS)
void block_mfma3(const float* __restrict__ X,
                 const float* __restrict__ Wattn,   // (4,32,24) d: k0..7 q8..15 v16..23
                 const float* __restrict__ Wproj,   // (32,32) [in][out]
                 const float* __restrict__ Wff1,    // (32,128)
                 const float* __restrict__ Wff2,    // (128,32)
                 float* __restrict__ Out,
                 int ntiles)
{
    __shared__ __align__(16) char smem[4 * 3 * LDS_CTX];   // 79,872 B -> 2 blocks/CU

    const int lane = threadIdx.x & 63;
    const int wid  = threadIdx.x >> 6;
    const int g    = lane >> 4;
    const int c    = lane & 15;
    char* WA = smem + wid * (3 * LDS_CTX);
    char* WB = WA + LDS_CTX;
    char* WC = WB + LDS_CTX;

    const float wscale = 0.5050098f;   // sqrt(32^-0.5 * log2(e))

    // ---- resident weight fragments (26 x bf16x8 = 104 regs) ----
    bf16x8 wqk[4], wv[2], wp[2], w1lo[4], w1hi[4], w2lo[4], w2hi[4];
    #pragma unroll
    for (int n = 0; n < 4; ++n)
        wqk[n] = gather_w(Wattn + n * 768 + c, 24, g, wscale);
    #pragma unroll
    for (int n = 0; n < 2; ++n) {
        int vch = 16 * n + c;
        wv[n] = gather_w(Wattn + (vch >> 3) * 768 + 16 + (vch & 7), 24, g, 1.f);
    }
    #pragma unroll
    for (int n = 0; n < 2; ++n)
        wp[n] = gather_w(Wproj + 16 * n + c, 32, g, 1.f);
    #pragma unroll
    for (int k = 0; k < 4; ++k) {
        w1lo[k] = gather_w(Wff1 + 16 * k + c, 128, g, 1.f);
        w1hi[k] = gather_w(Wff1 + 16 * (4 + k) + c, 128, g, 1.f);
        w2lo[k] = gather_w(Wff2 + k * 1024 + c, 32, g, 1.f);
        w2hi[k] = gather_w(Wff2 + k * 1024 + 16 + c, 32, g, 1.f);
    }

    // ---- per-lane constant masks ----
    f32x4 mf;
    #pragma unroll
    for (int r = 0; r < 4; ++r) {
        int key = 4 * g + r;
        mf[r] = ((key >> 3) == (c >> 3) && (key & 7) <= (c & 7)) ? 1.f : 0.f;
    }
    const int b0 = (lane < 16) ? -1 : 0;
    const int b1 = (((lane >> 3) & 1) == ((lane >> 5) & 1)) ? -1 : 0;
    const i32x4 mQK = {b0, b0, b0, b0};
    const i32x4 mPV = {b1, b1, b1, b1};

    const int tile0 = blockIdx.x * TPB + wid * TPW;
    if (tile0 >= ntiles) return;

    // prefetch triple 0's X B-frag sources: lane (g,c) needs X[c][8g..8g+7]
    int pA = tile0;
    int pB = (tile0 + 1 < ntiles) ? tile0 + 1 : ntiles - 1;
    int pC = (tile0 + 2 < ntiles) ? tile0 + 2 : ntiles - 1;
    f32x4 xrA0 = *(const f32x4*)(X + (size_t)pA * 512 + c * 32 + 8 * g);
    f32x4 xrA1 = *(const f32x4*)(X + (size_t)pA * 512 + c * 32 + 8 * g + 4);
    f32x4 xrB0 = *(const f32x4*)(X + (size_t)pB * 512 + c * 32 + 8 * g);
    f32x4 xrB1 = *(const f32x4*)(X + (size_t)pB * 512 + c * 32 + 8 * g + 4);
    f32x4 xrC0 = *(const f32x4*)(X + (size_t)pC * 512 + c * 32 + 8 * g);
    f32x4 xrC1 = *(const f32x4*)(X + (size_t)pC * 512 + c * 32 + 8 * g + 4);

    #pragma unroll 1
    for (int it = 0; it < TPW; it += 3) {
        const int iA = tile0 + it;
        const int iB = tile0 + it + 1;
        const int iC = tile0 + it + 2;
        const int ttA = (iA < ntiles) ? iA : ntiles - 1;
        const int ttB = (iB < ntiles) ? iB : ntiles - 1;
        const int ttC = (iC < ntiles) ? iC : ntiles - 1;
        const float* xgA = X + (size_t)ttA * 512;
        const float* xgB = X + (size_t)ttB * 512;
        const float* xgC = X + (size_t)ttC * 512;

        // residuals at C^T points (consumed in proj; latency covered by qkv+scores)
        f32x4 rxA0 = *(const f32x4*)(xgA + c * 32 + 4 * g);
        f32x4 rxA1 = *(const f32x4*)(xgA + c * 32 + 16 + 4 * g);
        f32x4 rxB0 = *(const f32x4*)(xgB + c * 32 + 4 * g);
        f32x4 rxB1 = *(const f32x4*)(xgB + c * 32 + 16 + 4 * g);
        f32x4 rxC0 = *(const f32x4*)(xgC + c * 32 + 4 * g);
        f32x4 rxC1 = *(const f32x4*)(xgC + c * 32 + 16 + 4 * g);

        // build X frags from prefetched sources (same convert path as verified)
        frag_u xfA, xfB, xfC;
        xfA.i = i32x4{ (int)pk_bf16(xrA0[0], xrA0[1]), (int)pk_bf16(xrA0[2], xrA0[3]),
                       (int)pk_bf16(xrA1[0], xrA1[1]), (int)pk_bf16(xrA1[2], xrA1[3]) };
        xfB.i = i32x4{ (int)pk_bf16(xrB0[0], xrB0[1]), (int)pk_bf16(xrB0[2], xrB0[3]),
                       (int)pk_bf16(xrB1[0], xrB1[1]), (int)pk_bf16(xrB1[2], xrB1[3]) };
        xfC.i = i32x4{ (int)pk_bf16(xrC0[0], xrC0[1]), (int)pk_bf16(xrC0[2], xrC0[3]),
                       (int)pk_bf16(xrC1[0], xrC1[1]), (int)pk_bf16(xrC1[2], xrC1[3]) };

        // prefetch next triple's X frag sources
        {
            int nA = (it + 3 < TPW && iA + 3 < ntiles) ? iA + 3 : ttA;
            int nB = (it + 4 < TPW && iB + 3 < ntiles) ? iB + 3 : ttB;
            int nC = (it + 5 < TPW && iC + 3 < ntiles) ? iC + 3 : ttC;
            xrA0 = *(const f32x4*)(X + (size_t)nA * 512 + c * 32 + 8 * g);
            xrA1 = *(const f32x4*)(X + (size_t)nA * 512 + c * 32 + 8 * g + 4);
            xrB0 = *(const f32x4*)(X + (size_t)nB * 512 + c * 32 + 8 * g);
            xrB1 = *(const f32x4*)(X + (size_t)nB * 512 + c * 32 + 8 * g + 4);
            xrC0 = *(const f32x4*)(X + (size_t)nC * 512 + c * 32 + 8 * g);
            xrC1 = *(const f32x4*)(X + (size_t)nC * 512 + c * 32 + 8 * g + 4);
        }

        ph_qkv(WA, c, g, wqk, wv, xfA.b);
        ph_qkv(WB, c, g, wqk, wv, xfB.b);
        ph_qkv(WC, c, g, wqk, wv, xfC.b);

        ph_scores(WA, c, g, mf, mQK);
        ph_scores(WB, c, g, mf, mQK);
        ph_scores(WC, c, g, mf, mQK);

        ph_pv(WA, c, g, mPV);
        ph_pv(WB, c, g, mPV);
        ph_pv(WC, c, g, mPV);

        f32x4 x2A[2], x2B[2], x2C[2];
        ph_proj(WA, c, g, wp, rxA0, rxA1, x2A);
        ph_proj(WB, c, g, wp, rxB0, rxB1, x2B);
        ph_proj(WC, c, g, wp, rxC0, rxC1, x2C);

        frag_u bfA; bfA.i = *(const i32x4_a*)(const void*)(WA + LDS_X2 + c * 80 + g * 16);
        frag_u bfB; bfB.i = *(const i32x4_a*)(const void*)(WB + LDS_X2 + c * 80 + g * 16);
        frag_u bfC; bfC.i = *(const i32x4_a*)(const void*)(WC + LDS_X2 + c * 80 + g * 16);

        ph_ff1h(WA, c, g, w1lo, 0, bfA.b);
        ph_ff1h(WB, c, g, w1lo, 0, bfB.b);
        ph_ff1h(WC, c, g, w1lo, 0, bfC.b);
        ph_ff1h(WA, c, g, w1hi, 4, bfA.b);
        ph_ff1h(WB, c, g, w1hi, 4, bfB.b);
        ph_ff1h(WC, c, g, w1hi, 4, bfC.b);

        ph_ff2_store(WA, c, g, w2lo, w2hi, x2A, Out + (size_t)ttA * 512, iA < ntiles);
        ph_ff2_store(WB, c, g, w2lo, w2hi, x2B, Out + (size_t)ttB * 512, iB < ntiles);
        ph_ff2_store(WC, c, g, w2lo, w2hi, x2C, Out + (size_t)ttC * 512, iC < ntiles);
    }
}

extern "C" void kernel_launch(void* const* d_in, const int* in_sizes, int n_in,
                              void* d_out, int out_size, void* d_ws, size_t ws_size,
                              hipStream_t stream) {
    (void)n_in; (void)out_size; (void)d_ws; (void)ws_size;
    const float* X     = (const float*)d_in[0];
    const float* Wattn = (const float*)d_in[1];
    const float* Wproj = (const float*)d_in[2];
    const float* Wff1  = (const float*)d_in[3];
    const float* Wff2  = (const float*)d_in[4];
    float* Out = (float*)d_out;

    const int nseq   = in_sizes[0] / 256;   // (b, 8, 32)
    const int ntiles = nseq / 2;            // 16 rows per tile
    const int blocks = (ntiles + TPB - 1) / TPB;
    block_mfma3<<<dim3(blocks), dim3(THREADS), 0, stream>>>(
        X, Wattn, Wproj, Wff1, Wff2, Out, ntiles);
}